// Round 1
// baseline (292.230 us; speedup 1.0000x reference)
//
#include <hip/hip_runtime.h>
#include <hip/hip_bf16.h>
#include <cstdint>
#include <cstddef>

// WideLSTM: N=32 blocks, I=64, H=128, B=16, T=256.
// 128 WGs = 32 blocks x 4 batch-groups (4 batches each), 512 thr (8 waves).
// Step-critical-path version: x-projection MFMAs (s=0,1) are hoisted into the
// PREVIOUS step's tail (overlapping the transcendental chain) and carried
// across the barrier as acpre = bias + Wih*x.  Post-barrier window is now
// only: ds_read h-frags -> two 2-deep MFMA chains -> selects -> trans ->
// ds_write h -> lgkm-only barrier.  x double-buffer retimed: staged 2 steps
// ahead of consumption (write@S = x(S+2) into xbuf[S&1], frag-read@S =
// x(S+1) from xbuf[(S+1)&1]); read->rewrite of a buffer is separated by a
// barrier, so 2 buffers still suffice.  x(0) is fragged straight from global
// in the prologue.  One lgkm-only barrier/step; c register-resident.

#define TSTEPS 256

typedef float  f32x4  __attribute__((ext_vector_type(4)));
typedef float  f32x2  __attribute__((ext_vector_type(2)));
typedef __bf16 bf16x8 __attribute__((ext_vector_type(8)));
typedef short  s16x8  __attribute__((ext_vector_type(8)));

union Frag { s16x8 s; bf16x8 b; };

#define KSIG -1.4426950408889634f   // -1/ln2 (sigmoid)
#define KTAN  2.8853900817779268f   //  2/ln2 (tanh)

__device__ __forceinline__ short f2bf(float f) {
  uint32_t u = __builtin_bit_cast(uint32_t, f);
  u += 0x7fffu + ((u >> 16) & 1u);
  return (short)(u >> 16);
}

// lgkm-only barrier: global loads/stores stay in flight across it
__device__ __forceinline__ void sync_lds() {
  asm volatile("s_waitcnt lgkmcnt(0)" ::: "memory");
  __builtin_amdgcn_s_barrier();
  asm volatile("" ::: "memory");
}

__device__ __forceinline__ float sig2(float z) {   // rcp(1 + exp2(z))
  return __builtin_amdgcn_rcpf(1.f + __builtin_amdgcn_exp2f(z));
}

__device__ __forceinline__ f32x4 mf(const Frag a, const Frag bb, f32x4 c) {
  return __builtin_amdgcn_mfma_f32_16x16x32_bf16(a.b, bb.b, c, 0, 0, 0);
}

__global__ __launch_bounds__(512, 2) void wide_lstm(
    const float* __restrict__ x,   const float* __restrict__ h0,
    const float* __restrict__ c0,  const float* __restrict__ wih,
    const float* __restrict__ whh, const float* __restrict__ bih,
    const float* __restrict__ bhh, float* __restrict__ out)
{
  const int n    = blockIdx.x & 31;
  const int bg   = blockIdx.x >> 5;      // batch group: batches [4bg, 4bg+4)
  const int tid  = threadIdx.x;
  const int w    = tid >> 6;             // wave 0..7: h-tile [16w, 16w+16)
  const int lane = tid & 63;
  const int col  = lane & 15;
  const int quad = lane >> 4;
  const int b4   = col & 3;              // batch within group
  const int e2   = col >> 2;             // acc row r this lane keeps (0..3)
  const int hloc = 4 * quad + e2;        // h within wave's 16-tile
  const int hgl  = 16 * w + hloc;        // h within block (0..127)
  const int b    = 4 * bg + b4;          // global batch this lane updates

  // h: 4 rows x stride 144 shorts (bank-tuned: 8*b4+4*quad, <=2-way)
  __shared__ alignas(16) short hbuf[2][4 * 144];
  // x: 4 rows x stride 96 shorts (16*b4+16*s+4*quad, <=2-way)
  __shared__ alignas(16) short xbuf[2][4 * 96];

  // ---- weights -> persistent A-fragments ----
  // A tile j (gate type): lane holds W[g = 128j + 16w + col][k = 32s + quad*8 + jj]
  Frag wfr[6][4];
#pragma unroll
  for (int j = 0; j < 4; ++j) {
    const int g = 128 * j + 16 * w + col;
#pragma unroll
    for (int s = 0; s < 6; ++s) {
      const int k0 = 32 * s + quad * 8;
      const float* p = (s < 2) ? (wih + (size_t)(n * 512 + g) * 64  + k0)
                               : (whh + (size_t)(n * 512 + g) * 128 + (k0 - 64));
      const f32x4 lo = *(const f32x4*)p;
      const f32x4 hi = *(const f32x4*)(p + 4);
      Frag f;
      f.s[0]=f2bf(lo[0]); f.s[1]=f2bf(lo[1]); f.s[2]=f2bf(lo[2]); f.s[3]=f2bf(lo[3]);
      f.s[4]=f2bf(hi[0]); f.s[5]=f2bf(hi[1]); f.s[6]=f2bf(hi[2]); f.s[7]=f2bf(hi[3]);
      wfr[s][j] = f;
    }
  }

  // ---- bias in MFMA C-layout (row = quad*4+r, col-independent) ----
  f32x4 cb[4];
#pragma unroll
  for (int j = 0; j < 4; ++j) {
    const int base = n * 512 + 128 * j + 16 * w + quad * 4;
    const f32x4 b1 = *(const f32x4*)(bih + base);
    const f32x4 b2 = *(const f32x4*)(bhh + base);
#pragma unroll
    for (int r = 0; r < 4; ++r) cb[j][r] = b1[r] + b2[r];
  }
  const f32x4 kzero = (f32x4){0.f, 0.f, 0.f, 0.f};

  // ---- init h(0), c(0) ----
  if (tid < 256) {
    const int bi = tid >> 6, j2 = (tid & 63) * 2;
    const f32x2 hv = *(const f32x2*)(h0 + (size_t)(4 * bg + bi) * 4096 + n * 128 + j2);
    *(uint32_t*)&hbuf[0][bi * 144 + j2] =
        (uint32_t)(uint16_t)f2bf(hv[0]) | ((uint32_t)(uint16_t)f2bf(hv[1]) << 16);
  }
  // ---- x staging: prologue stages x(1) -> xbuf[1]; xr = x(2); cursor x(3) ----
  const int bq = tid >> 6;               // staging batch (tid<256)
  const int kq = tid & 63;               // staging k
  const float* xp = x + (size_t)(4 * bg + bq) * (TSTEPS * 2048) + n * 64 + kq;
  float xr = 0.f;
  if (tid < 256) {
    xbuf[1][bq * 96 + kq] = f2bf(xp[2048]);   // x(1)
    xr = xp[2 * 2048];                        // x(2)
  }
  const float* xnext = xp + 3 * 2048;         // cursor at x(3)
  float cg = c0[(size_t)b * 4096 + n * 128 + hgl];

  // ---- acpre(0) = bias + Wih*x(0), x(0) fragged directly from global ----
  f32x4 acpre[4];
  {
    const float* q = x + (size_t)b * (TSTEPS * 2048) + n * 64 + 8 * quad;
    const f32x4 a0 = *(const f32x4*)q;
    const f32x4 a1 = *(const f32x4*)(q + 4);
    const f32x4 a2 = *(const f32x4*)(q + 32);
    const f32x4 a3 = *(const f32x4*)(q + 36);
    Frag xf0, xf1;
#pragma unroll
    for (int r = 0; r < 4; ++r) {
      xf0.s[r]     = f2bf(a0[r]);
      xf0.s[4 + r] = f2bf(a1[r]);
      xf1.s[r]     = f2bf(a2[r]);
      xf1.s[4 + r] = f2bf(a3[r]);
    }
#pragma unroll
    for (int j = 0; j < 4; ++j)
      acpre[j] = mf(wfr[1][j], xf1, mf(wfr[0][j], xf0, cb[j]));
  }
  __syncthreads();

  const int xoff  = b4 * 96  + quad * 8;     // x B-frag base (s=0,1)
  const int hoff  = b4 * 144 + quad * 8;     // h B-frag base (s=2..5)
  const int sxoff = bq * 96 + kq;            // x staging slot (tid<256)
  const int hwoff = b4 * 144 + hgl;          // h write slot
  float* outp = out + (size_t)b * (TSTEPS * 4096) + n * 128 + hgl;
  float ho = 0.f;
  const bool m1 = (e2 & 1), m2 = (e2 & 2);

  // Step S (CUR=S&1): read h(S) from hbuf[CUR], x(S+1) frags from xbuf[NXT]
  // (written at S-1, barrier between); stage x(S+2) into xbuf[CUR] (last read
  // at top of S-1, barrier between).  Tail computes acpre(S+1).
#define LSTM_STEP(CUR, NXT, S)                                               \
  {                                                                          \
    Frag hf0, hf1, hf2, hf3;                                                 \
    hf0.s = *(const s16x8*)&hbuf[CUR][hoff];                                 \
    hf1.s = *(const s16x8*)&hbuf[CUR][hoff + 32];                            \
    hf2.s = *(const s16x8*)&hbuf[CUR][hoff + 64];                            \
    hf3.s = *(const s16x8*)&hbuf[CUR][hoff + 96];                            \
    if (tid < 256) {                                                         \
      xbuf[CUR][sxoff] = f2bf(xr);                                           \
      if ((S) + 3 < TSTEPS) { xr = *xnext; xnext += 2048; }                  \
    }                                                                        \
    f32x4 ac1[4], ac2[4];                                                    \
    _Pragma("unroll") for (int j = 0; j < 4; ++j) {                          \
      ac1[j] = mf(wfr[2][j], hf0, acpre[j]);                                 \
      ac2[j] = mf(wfr[4][j], hf2, kzero);                                    \
    }                                                                        \
    _Pragma("unroll") for (int j = 0; j < 4; ++j) {                          \
      ac1[j] = mf(wfr[3][j], hf1, ac1[j]);                                   \
      ac2[j] = mf(wfr[5][j], hf3, ac2[j]);                                   \
    }                                                                        \
    __builtin_amdgcn_sched_barrier(0);  /* keep x-MFMAs out of the h window */\
    Frag xg0, xg1;                                                           \
    xg0.s = *(const s16x8*)&xbuf[NXT][xoff];                                 \
    xg1.s = *(const s16x8*)&xbuf[NXT][xoff + 32];                            \
    float pre[4];                                                            \
    _Pragma("unroll") for (int j = 0; j < 4; ++j) {                          \
      const float u01 = m1 ? ac1[j][1] : ac1[j][0];                          \
      const float u23 = m1 ? ac1[j][3] : ac1[j][2];                          \
      const float v01 = m1 ? ac2[j][1] : ac2[j][0];                          \
      const float v23 = m1 ? ac2[j][3] : ac2[j][2];                          \
      pre[j] = (m2 ? u23 : u01) + (m2 ? v23 : v01);                          \
    }                                                                        \
    const float si = sig2(KSIG * pre[0]);                                    \
    const float sf = sig2(KSIG * pre[1]);                                    \
    const float sg = sig2(KTAN * pre[2]);                                    \
    const float so = sig2(KSIG * pre[3]);                                    \
    float cn = __builtin_fmaf(sf, cg, si);                                   \
    cn = __builtin_fmaf(-2.f, si * sg, cn);                                  \
    cg = cn;                                                                 \
    ho = so * __builtin_fmaf(-2.f, sig2(KTAN * cn), 1.f);                    \
    _Pragma("unroll") for (int j = 0; j < 4; ++j)                            \
      acpre[j] = mf(wfr[0][j], xg0, cb[j]);                                  \
    _Pragma("unroll") for (int j = 0; j < 4; ++j)                            \
      acpre[j] = mf(wfr[1][j], xg1, acpre[j]);                               \
    hbuf[NXT][hwoff] = f2bf(ho);                                             \
    *outp = ho;                                                              \
    outp += 4096;                                                            \
    sync_lds();                                                              \
  }

  for (int t = 0; t < TSTEPS; t += 2) {
    LSTM_STEP(0, 1, t);
    LSTM_STEP(1, 0, t + 1);
  }
#undef LSTM_STEP

  // ---- h_n / c_n (one float per lane) ----
  out[16777216 +         (size_t)b * 4096 + n * 128 + hgl] = ho;
  out[16777216 + 65536 + (size_t)b * 4096 + n * 128 + hgl] = cg;
}

extern "C" void kernel_launch(void* const* d_in, const int* in_sizes, int n_in,
                              void* d_out, int out_size, void* d_ws, size_t ws_size,
                              hipStream_t stream) {
  const float* x   = (const float*)d_in[0];
  const float* h0  = (const float*)d_in[1];
  const float* c0  = (const float*)d_in[2];
  const float* wih = (const float*)d_in[3];
  const float* whh = (const float*)d_in[4];
  const float* bih = (const float*)d_in[5];
  const float* bhh = (const float*)d_in[6];
  float* out = (float*)d_out;
  wide_lstm<<<128, 512, 0, stream>>>(x, h0, c0, wih, whh, bih, bhh, out);
}

// Round 2
// 267.867 us; speedup vs baseline: 1.0910x; 1.0910x over previous
//
#include <hip/hip_runtime.h>
#include <hip/hip_bf16.h>
#include <cstdint>
#include <cstddef>

// WideLSTM: N=32 blocks, I=64, H=128, B=16, T=256.
// 128 WGs = 32 blocks x 4 batch-groups, now 1024 thr = 16 waves = 4 waves/SIMD.
// K-split wave pairs: wave w (0..7) holds K-slices s=0,1,2 (x-proj s0,s1 run
// in the step tail as acpre; s2 = Whh k[0,32) in-window); partner wave w+8
// holds s=3,4,5 (Whh k[32,128), 3-deep chains, C=0).  Partner pre-selects its
// lane's useful element (e2) and ships ONE f32x4/lane via pbuf; wave w adds
// and runs the epilogue.  2 barriers/step (B: partials ready, A': h/x bufs
// ready).  4 waves/SIMD de-synchronizes phases: w' MFMAs cover w epilogue,
// w tail x-MFMAs cover w' idle.  x global loads on w' waves, out stores on
// w waves (separate vmcnt queues).  c register-resident.

#define TSTEPS 256

typedef float  f32x4  __attribute__((ext_vector_type(4)));
typedef float  f32x2  __attribute__((ext_vector_type(2)));
typedef __bf16 bf16x8 __attribute__((ext_vector_type(8)));
typedef short  s16x8  __attribute__((ext_vector_type(8)));

union Frag { s16x8 s; bf16x8 b; };

#define KSIG -1.4426950408889634f   // -1/ln2 (sigmoid)
#define KTAN  2.8853900817779268f   //  2/ln2 (tanh)

__device__ __forceinline__ short f2bf(float f) {
  uint32_t u = __builtin_bit_cast(uint32_t, f);
  u += 0x7fffu + ((u >> 16) & 1u);
  return (short)(u >> 16);
}

// lgkm-only barrier: global loads/stores stay in flight across it
__device__ __forceinline__ void sync_lds() {
  asm volatile("s_waitcnt lgkmcnt(0)" ::: "memory");
  __builtin_amdgcn_s_barrier();
  asm volatile("" ::: "memory");
}

__device__ __forceinline__ float sig2(float z) {   // rcp(1 + exp2(z))
  return __builtin_amdgcn_rcpf(1.f + __builtin_amdgcn_exp2f(z));
}

__device__ __forceinline__ f32x4 mf(const Frag a, const Frag bb, f32x4 c) {
  return __builtin_amdgcn_mfma_f32_16x16x32_bf16(a.b, bb.b, c, 0, 0, 0);
}

__device__ __forceinline__ float sel4(const f32x4 a, bool m1, bool m2) {
  const float u01 = m1 ? a[1] : a[0];
  const float u23 = m1 ? a[3] : a[2];
  return m2 ? u23 : u01;
}

__global__ __launch_bounds__(1024, 4) void wide_lstm(
    const float* __restrict__ x,   const float* __restrict__ h0,
    const float* __restrict__ c0,  const float* __restrict__ wih,
    const float* __restrict__ whh, const float* __restrict__ bih,
    const float* __restrict__ bhh, float* __restrict__ out)
{
  const int n    = blockIdx.x & 31;
  const int bg   = blockIdx.x >> 5;      // batch group: batches [4bg, 4bg+4)
  const int tid  = threadIdx.x;
  const int wv   = tid >> 6;             // wave 0..15
  const int w    = wv & 7;               // pair id / h-tile [16w, 16w+16)
  const bool isw = (wv < 8);             // front half: epilogue owner
  const int lane = tid & 63;
  const int col  = lane & 15;
  const int quad = lane >> 4;
  const int b4   = col & 3;              // batch within group
  const int e2   = col >> 2;             // acc row r this lane keeps (0..3)
  const int hloc = 4 * quad + e2;
  const int hgl  = 16 * w + hloc;        // h within block (0..127)
  const int b    = 4 * bg + b4;          // global batch this lane updates

  // h: 4 rows x stride 144 shorts (bank-tuned); x: 4 rows x stride 96
  __shared__ alignas(16) short hbuf[2][4 * 144];
  __shared__ alignas(16) short xbuf[2][4 * 96];
  // pair-exchange partials: one f32x4 per w' lane, contiguous b128
  __shared__ alignas(16) float pbuf[8][64][4];

  // ---- weights -> persistent A-fragments (3 K-slices per wave) ----
  // w: s = 0,1,2 (wih k0-63 + whh k0-31); w': s = 3,4,5 (whh k32-127)
  Frag wfr[3][4];
#pragma unroll
  for (int j = 0; j < 4; ++j) {
    const int g = 128 * j + 16 * w + col;
#pragma unroll
    for (int sl = 0; sl < 3; ++sl) {
      const int s = isw ? sl : sl + 3;
      const int k0 = 32 * s + quad * 8;
      const float* p = (s < 2) ? (wih + (size_t)(n * 512 + g) * 64  + k0)
                               : (whh + (size_t)(n * 512 + g) * 128 + (k0 - 64));
      const f32x4 lo = *(const f32x4*)p;
      const f32x4 hi = *(const f32x4*)(p + 4);
      Frag f;
      f.s[0]=f2bf(lo[0]); f.s[1]=f2bf(lo[1]); f.s[2]=f2bf(lo[2]); f.s[3]=f2bf(lo[3]);
      f.s[4]=f2bf(hi[0]); f.s[5]=f2bf(hi[1]); f.s[6]=f2bf(hi[2]); f.s[7]=f2bf(hi[3]);
      wfr[sl][j] = f;
    }
  }

  const int hoff  = b4 * 144 + quad * 8;     // h B-frag base
  const int hwoff = b4 * 144 + hgl;          // h write slot
  const int xoff  = b4 * 96  + quad * 8;     // x B-frag base
  const bool m1 = (e2 & 1), m2 = (e2 & 2);
  const f32x4 kzero = (f32x4){0.f, 0.f, 0.f, 0.f};

  f32x4 cb[4], acpre[4];
  float cg = 0.f, ho = 0.f;
  float* outp = nullptr;
  float xr = 0.f;
  const float* xnext = nullptr;

  if (isw) {
    // ---- bias in MFMA C-layout ----
#pragma unroll
    for (int j = 0; j < 4; ++j) {
      const int base = n * 512 + 128 * j + 16 * w + quad * 4;
      const f32x4 b1 = *(const f32x4*)(bih + base);
      const f32x4 b2 = *(const f32x4*)(bhh + base);
#pragma unroll
      for (int r = 0; r < 4; ++r) cb[j][r] = b1[r] + b2[r];
    }
    // ---- init h(0) ----
    if (tid < 256) {
      const int bi = tid >> 6, j2 = (tid & 63) * 2;
      const f32x2 hv = *(const f32x2*)(h0 + (size_t)(4 * bg + bi) * 4096 + n * 128 + j2);
      *(uint32_t*)&hbuf[0][bi * 144 + j2] =
          (uint32_t)(uint16_t)f2bf(hv[0]) | ((uint32_t)(uint16_t)f2bf(hv[1]) << 16);
    }
    cg = c0[(size_t)b * 4096 + n * 128 + hgl];
    // ---- acpre(0) = bias + Wih*x(0), fragged direct from global ----
    {
      const float* q = x + (size_t)b * (TSTEPS * 2048) + n * 64 + 8 * quad;
      const f32x4 a0 = *(const f32x4*)q;
      const f32x4 a1 = *(const f32x4*)(q + 4);
      const f32x4 a2 = *(const f32x4*)(q + 32);
      const f32x4 a3 = *(const f32x4*)(q + 36);
      Frag xf0, xf1;
#pragma unroll
      for (int r = 0; r < 4; ++r) {
        xf0.s[r]     = f2bf(a0[r]);
        xf0.s[4 + r] = f2bf(a1[r]);
        xf1.s[r]     = f2bf(a2[r]);
        xf1.s[4 + r] = f2bf(a3[r]);
      }
#pragma unroll
      for (int j = 0; j < 4; ++j)
        acpre[j] = mf(wfr[1][j], xf1, mf(wfr[0][j], xf0, cb[j]));
    }
    outp = out + (size_t)b * (TSTEPS * 4096) + n * 128 + hgl;
  } else if (tid < 768) {
    // ---- x staging init (waves 8-11): x(1)->xbuf[1]; xr=x(2); cursor x(3) ----
    const int bq = (tid >> 6) & 3;
    const int kq = tid & 63;
    const float* xp = x + (size_t)(4 * bg + bq) * (TSTEPS * 2048) + n * 64 + kq;
    xbuf[1][bq * 96 + kq] = f2bf(xp[2048]);
    xr = xp[2 * 2048];
    xnext = xp + 3 * 2048;
  }
  __syncthreads();   // barrier A of step 0

  if (isw) {
    // ================= epilogue-owner wave loop =================
    // Per step: [A] ds_read hf0 -> 4 MFMA (acpre + Whh[0,32)h) -> sel
    //           [B] + partner f32x4 -> trans epilogue -> write h, out
    //               tail: xg reads + 8 acpre MFMAs (cover w' idle) [A']
#define WSTEP(CUR, NXT, S)                                                   \
  {                                                                          \
    Frag hf0;                                                                \
    hf0.s = *(const s16x8*)&hbuf[CUR][hoff];                                 \
    f32x4 ac1[4];                                                            \
    _Pragma("unroll") for (int j = 0; j < 4; ++j)                            \
      ac1[j] = mf(wfr[2][j], hf0, acpre[j]);                                 \
    float pre[4];                                                            \
    _Pragma("unroll") for (int j = 0; j < 4; ++j)                            \
      pre[j] = sel4(ac1[j], m1, m2);                                         \
    sync_lds(); /* B: partner partials ready */                              \
    const f32x4 vv = *(const f32x4*)&pbuf[w][lane][0];                       \
    pre[0] += vv[0]; pre[1] += vv[1]; pre[2] += vv[2]; pre[3] += vv[3];      \
    const float si = sig2(KSIG * pre[0]);                                    \
    const float sf = sig2(KSIG * pre[1]);                                    \
    const float sg = sig2(KTAN * pre[2]);                                    \
    const float so = sig2(KSIG * pre[3]);                                    \
    float cn = __builtin_fmaf(sf, cg, si);                                   \
    cn = __builtin_fmaf(-2.f, si * sg, cn);                                  \
    cg = cn;                                                                 \
    ho = so * __builtin_fmaf(-2.f, sig2(KTAN * cn), 1.f);                    \
    hbuf[NXT][hwoff] = f2bf(ho);                                             \
    *outp = ho;                                                              \
    outp += 4096;                                                            \
    Frag xg0, xg1;                                                           \
    xg0.s = *(const s16x8*)&xbuf[NXT][xoff];                                 \
    xg1.s = *(const s16x8*)&xbuf[NXT][xoff + 32];                            \
    _Pragma("unroll") for (int j = 0; j < 4; ++j)                            \
      acpre[j] = mf(wfr[0][j], xg0, cb[j]);                                  \
    _Pragma("unroll") for (int j = 0; j < 4; ++j)                            \
      acpre[j] = mf(wfr[1][j], xg1, acpre[j]);                               \
    sync_lds(); /* A' */                                                     \
  }
    for (int t = 0; t < TSTEPS; t += 2) {
      WSTEP(0, 1, t);
      WSTEP(1, 0, t + 1);
    }
#undef WSTEP
    // ---- h_n / c_n (one float per w lane) ----
    out[16777216 +         (size_t)b * 4096 + n * 128 + hgl] = ho;
    out[16777216 + 65536 + (size_t)b * 4096 + n * 128 + hgl] = cg;
  } else {
    // ================= partner wave loop =================
    // Per step: [A] ds_read hf1-3, stage x, 12 MFMA (3-deep, C=0),
    //           sel -> pbuf write [B] (idle) [A']
    const int sxoff = ((tid >> 6) & 3) * 96 + (tid & 63);
    const bool stg = (tid < 768);
#define VSTEP(CUR, NXT, S)                                                   \
  {                                                                          \
    Frag hf1, hf2, hf3;                                                      \
    hf1.s = *(const s16x8*)&hbuf[CUR][hoff + 32];                            \
    hf2.s = *(const s16x8*)&hbuf[CUR][hoff + 64];                            \
    hf3.s = *(const s16x8*)&hbuf[CUR][hoff + 96];                            \
    if (stg) {                                                               \
      xbuf[CUR][sxoff] = f2bf(xr);                                           \
      if ((S) + 3 < TSTEPS) { xr = *xnext; xnext += 2048; }                  \
    }                                                                        \
    f32x4 ac[4];                                                             \
    _Pragma("unroll") for (int j = 0; j < 4; ++j)                            \
      ac[j] = mf(wfr[0][j], hf1, kzero);                                     \
    _Pragma("unroll") for (int j = 0; j < 4; ++j)                            \
      ac[j] = mf(wfr[1][j], hf2, ac[j]);                                     \
    _Pragma("unroll") for (int j = 0; j < 4; ++j)                            \
      ac[j] = mf(wfr[2][j], hf3, ac[j]);                                     \
    f32x4 vv;                                                                \
    vv[0] = sel4(ac[0], m1, m2);                                             \
    vv[1] = sel4(ac[1], m1, m2);                                             \
    vv[2] = sel4(ac[2], m1, m2);                                             \
    vv[3] = sel4(ac[3], m1, m2);                                             \
    *(f32x4*)&pbuf[w][lane][0] = vv;                                         \
    sync_lds(); /* B */                                                      \
    sync_lds(); /* A' */                                                     \
  }
    for (int t = 0; t < TSTEPS; t += 2) {
      VSTEP(0, 1, t);
      VSTEP(1, 0, t + 1);
    }
#undef VSTEP
  }
}

extern "C" void kernel_launch(void* const* d_in, const int* in_sizes, int n_in,
                              void* d_out, int out_size, void* d_ws, size_t ws_size,
                              hipStream_t stream) {
  const float* x   = (const float*)d_in[0];
  const float* h0  = (const float*)d_in[1];
  const float* c0  = (const float*)d_in[2];
  const float* wih = (const float*)d_in[3];
  const float* whh = (const float*)d_in[4];
  const float* bih = (const float*)d_in[5];
  const float* bhh = (const float*)d_in[6];
  float* out = (float*)d_out;
  wide_lstm<<<128, 1024, 0, stream>>>(x, h0, c0, wih, whh, bih, bhh, out);
}